// Round 9
// baseline (160.725 us; speedup 1.0000x reference)
//
#include <hip/hip_runtime.h>

// NeighborRoutingAgg: N=50000, M=32, D=128, 3 routing iters.
// Round 9 (= r8 resubmit + safer asm): r7 showed the compiler kept z PACKED
// (VGPR=56) and rematerialized the bf16->f32 unpack at every use (~320 extra
// VALU ops/wave); float2 struct math didn't trigger packed-f32. Fixes:
//   1) scalar asm volatile("" : "+v"(lo), "+v"(hi)) after unpack -> values
//      opaque, remat impossible, zp dies, z2 (64 VGPR) stays resident.
//      (Scalar operands, not 64-bit vector operand: removes any inline-asm
//      constraint ambiguity suspected in the r8 container failure.)
//   2) ext_vector_type(2) float math -> v_pk_fma_f32/v_pk_add_f32 VOP3P,
//      halving FMA issue count.
// Numerics bit-identical to r6/r7 (absmax 1.95e-3). Fallback f32 path kept.

#define M_NB 32
#define D_DIM 128
#define EPSN 1e-12f

typedef float f32x2 __attribute__((ext_vector_type(2)));

// ---------- bf16-table path ----------

// Kernel A: xn table (bf16, RN-even) + invn. One wave per row.
__global__ __launch_bounds__(256) void prep_kernel(const float* __restrict__ x,
                                                   unsigned int* __restrict__ xnb,
                                                   float* __restrict__ invn, int n) {
    int row  = (int)((blockIdx.x * blockDim.x + threadIdx.x) >> 6);
    int lane = threadIdx.x & 63;
    if (row >= n) return;
    float2 v = *reinterpret_cast<const float2*>(x + (size_t)row * D_DIM + 2 * lane);
    float s = v.x * v.x + v.y * v.y;
    #pragma unroll
    for (int off = 32; off; off >>= 1) s += __shfl_xor(s, off);
    float inv = 1.0f / fmaxf(sqrtf(s), EPSN);
    if (lane == 0) invn[row] = inv;
    float a = v.x * inv, b = v.y * inv;
    unsigned int ba = __builtin_bit_cast(unsigned int, a);
    unsigned int bb = __builtin_bit_cast(unsigned int, b);
    unsigned int ra = (ba + 0x7fffu + ((ba >> 16) & 1u)) >> 16;          // low  16: dim 2l
    unsigned int rb = (bb + 0x7fffu + ((bb >> 16) & 1u)) & 0xffff0000u;  // high 16: dim 2l+1
    xnb[(size_t)row * 64 + lane] = ra | rb;
}

// Kernel B: one wave per node. g=lane>>4 (row group), t=lane&15 (dim slice 8t..8t+7).
__global__ __launch_bounds__(256, 4) void routing_bf16_kernel(const float* __restrict__ x,
                                                              const int* __restrict__ nb,
                                                              const unsigned int* __restrict__ xnb,
                                                              const float* __restrict__ invn,
                                                              float* __restrict__ out, int n) {
    int node = (int)((blockIdx.x * blockDim.x + threadIdx.x) >> 6);
    int lane = threadIdx.x & 63;
    if (node >= n) return;
    int g = lane >> 4, t = lane & 15;

    // x_nb dtype probe (int64-as-int32: odd words all zero; ids are 1..N, never 0)
    int probe = nb[lane];
    bool sig  = (lane & 1) ? (probe == 0) : (probe != 0);
    bool is64 = __all(sig);

    size_t base = (size_t)node * M_NB + (lane & 31);
    int j = (is64 ? nb[2 * base] : nb[base]) - 1;

    // Gather: instruction i loads row 4i+g; lane reads 16B = dims 8t..8t+7 (bf16x8).
    uint4 zp[8];
    #pragma unroll
    for (int i = 0; i < 8; ++i) {
        int jm = __shfl(j, i * 4 + g);
        zp[i] = *reinterpret_cast<const uint4*>(xnb + (size_t)jm * 64 + t * 4);
    }

    // Self xn (f32-exact): dims 8t..8t+7, as 4 f32x2 pairs
    f32x2 xn2[4];
    {
        float4 a = *reinterpret_cast<const float4*>(x + (size_t)node * D_DIM + t * 8);
        float4 b = *reinterpret_cast<const float4*>(x + (size_t)node * D_DIM + t * 8 + 4);
        float inv = invn[node];
        xn2[0] = (f32x2){a.x * inv, a.y * inv};
        xn2[1] = (f32x2){a.z * inv, a.w * inv};
        xn2[2] = (f32x2){b.x * inv, b.y * inv};
        xn2[3] = (f32x2){b.z * inv, b.w * inv};
    }

    // Unpack bf16 -> f32 ONCE; scalar keep-alive asm makes the unpacked values
    // opaque so the compiler cannot rematerialize from zp (zp dies, z2 lives).
    f32x2 z2[8][4];
    #pragma unroll
    for (int i = 0; i < 8; ++i) {
        unsigned int w[4] = { zp[i].x, zp[i].y, zp[i].z, zp[i].w };
        #pragma unroll
        for (int c = 0; c < 4; ++c) {
            float lo = __builtin_bit_cast(float, w[c] << 16);
            float hi = __builtin_bit_cast(float, w[c] & 0xffff0000u);
            asm volatile("" : "+v"(lo), "+v"(hi));
            z2[i][c] = (f32x2){lo, hi};
        }
    }

    // ---- it0: u = mean_m(z) + xn (cross-group reduce xor16, xor32) ----
    f32x2 u2[4];
    #pragma unroll
    for (int c = 0; c < 4; ++c) {
        f32x2 s = (f32x2){0.f, 0.f};
        #pragma unroll
        for (int i = 0; i < 8; ++i) s += z2[i][c];
        s.x += __shfl_xor(s.x, 16);  s.y += __shfl_xor(s.y, 16);
        s.x += __shfl_xor(s.x, 32);  s.y += __shfl_xor(s.y, 32);
        u2[c] = s * (1.0f / M_NB) + xn2[c];
    }
    // squash (reduce over t: xor 1,2,4,8)
    {
        f32x2 q = u2[0] * u2[0] + u2[1] * u2[1] + u2[2] * u2[2] + u2[3] * u2[3];
        float sq = q.x + q.y;
        #pragma unroll
        for (int off = 1; off <= 8; off <<= 1) sq += __shfl_xor(sq, off);
        float scale = sq / ((sq + 1.0f) * fmaxf(sqrtf(sq), EPSN));
        #pragma unroll
        for (int c = 0; c < 4; ++c) u2[c] *= scale;
    }

    // ---- iterations 1, 2 ----
    #pragma unroll
    for (int it = 1; it < 3; ++it) {
        // dots: p[i] = z[4i+g] . u (packed fma then 16-lane reduce)
        float p[8];
        #pragma unroll
        for (int i = 0; i < 8; ++i) {
            f32x2 a = z2[i][0] * u2[0];
            a += z2[i][1] * u2[1];
            a += z2[i][2] * u2[2];
            a += z2[i][3] * u2[3];
            float pd = a.x + a.y;
            #pragma unroll
            for (int off = 1; off <= 8; off <<= 1) pd += __shfl_xor(pd, off);
            p[i] = pd;
        }
        // softmax over 32 rows: 8 local x 4 groups
        float mx = p[0];
        #pragma unroll
        for (int i = 1; i < 8; ++i) mx = fmaxf(mx, p[i]);
        mx = fmaxf(mx, __shfl_xor(mx, 16));
        mx = fmaxf(mx, __shfl_xor(mx, 32));
        float sum = 0.f;
        #pragma unroll
        for (int i = 0; i < 8; ++i) { p[i] = __expf(p[i] - mx); sum += p[i]; }
        sum += __shfl_xor(sum, 16);
        sum += __shfl_xor(sum, 32);
        float rs = 1.0f / sum;
        // weighted sum + cross-group reduce
        #pragma unroll
        for (int c = 0; c < 4; ++c) {
            f32x2 a = (f32x2){0.f, 0.f};
            #pragma unroll
            for (int i = 0; i < 8; ++i) {
                f32x2 pv = (f32x2){p[i], p[i]};
                a += pv * z2[i][c];
            }
            a.x += __shfl_xor(a.x, 16);  a.y += __shfl_xor(a.y, 16);
            a.x += __shfl_xor(a.x, 32);  a.y += __shfl_xor(a.y, 32);
            u2[c] = a * rs + xn2[c];
        }
        if (it < 2) {
            f32x2 q = u2[0] * u2[0] + u2[1] * u2[1] + u2[2] * u2[2] + u2[3] * u2[3];
            float sq = q.x + q.y;
            #pragma unroll
            for (int off = 1; off <= 8; off <<= 1) sq += __shfl_xor(sq, off);
            float scale = sq / ((sq + 1.0f) * fmaxf(sqrtf(sq), EPSN));
            #pragma unroll
            for (int c = 0; c < 4; ++c) u2[c] *= scale;
        }
    }

    // write: groups 0/1 emit 32 lanes x 16B = full 512B row (static indices only)
    if (g == 0) {
        *reinterpret_cast<float4*>(out + (size_t)node * D_DIM + t * 8) =
            make_float4(u2[0].x, u2[0].y, u2[1].x, u2[1].y);
    } else if (g == 1) {
        *reinterpret_cast<float4*>(out + (size_t)node * D_DIM + t * 8 + 4) =
            make_float4(u2[2].x, u2[2].y, u2[3].x, u2[3].y);
    }
}

// ---------- fallback f32 path (round-4, proven) ----------

__global__ __launch_bounds__(256) void invnorm_kernel(const float* __restrict__ x,
                                                      float* __restrict__ invn, int n) {
    int row  = (int)((blockIdx.x * blockDim.x + threadIdx.x) >> 6);
    int lane = threadIdx.x & 63;
    if (row >= n) return;
    float2 v = *reinterpret_cast<const float2*>(x + (size_t)row * D_DIM + 2 * lane);
    float s = v.x * v.x + v.y * v.y;
    #pragma unroll
    for (int off = 32; off; off >>= 1) s += __shfl_xor(s, off);
    if (lane == 0) invn[row] = 1.0f / fmaxf(sqrtf(s), EPSN);
}

__global__ __launch_bounds__(256) void routing_kernel(const float* __restrict__ x,
                                                      const int* __restrict__ nb,
                                                      const float* __restrict__ invn,
                                                      float* __restrict__ out, int n) {
    int node = (int)((blockIdx.x * blockDim.x + threadIdx.x) >> 6);
    int lane = threadIdx.x & 63;
    if (node >= n) return;

    int probe = nb[lane];
    bool sig  = (lane & 1) ? (probe == 0) : (probe != 0);
    bool is64 = __all(sig);

    size_t base = (size_t)node * M_NB + (lane & 31);
    int j = (is64 ? nb[2 * base] : nb[base]) - 1;
    float vinv = invn[j];

    float2 z[M_NB];
    #pragma unroll
    for (int m = 0; m < M_NB; ++m) {
        int   jm = __shfl(j, m);
        float im = __shfl(vinv, m);
        float2 v = *reinterpret_cast<const float2*>(x + (size_t)jm * D_DIM + 2 * lane);
        z[m] = make_float2(v.x * im, v.y * im);
    }

    float2 xs = *reinterpret_cast<const float2*>(x + (size_t)node * D_DIM + 2 * lane);
    float  si = invn[node];
    float2 xn = make_float2(xs.x * si, xs.y * si);

    float2 u = make_float2(0.f, 0.f);
    #pragma unroll
    for (int m = 0; m < M_NB; ++m) { u.x += z[m].x; u.y += z[m].y; }
    u.x = u.x * (1.0f / M_NB) + xn.x;
    u.y = u.y * (1.0f / M_NB) + xn.y;
    {
        float sq = u.x * u.x + u.y * u.y;
        #pragma unroll
        for (int off = 32; off; off >>= 1) sq += __shfl_xor(sq, off);
        float scale = sq / ((sq + 1.0f) * fmaxf(sqrtf(sq), EPSN));
        u.x *= scale; u.y *= scale;
    }
    #pragma unroll
    for (int it = 1; it < 3; ++it) {
        float p[M_NB];
        #pragma unroll
        for (int m = 0; m < M_NB; ++m) {
            float tt = z[m].x * u.x + z[m].y * u.y;
            #pragma unroll
            for (int off = 32; off; off >>= 1) tt += __shfl_xor(tt, off);
            p[m] = tt;
        }
        float mx = p[0];
        #pragma unroll
        for (int m = 1; m < M_NB; ++m) mx = fmaxf(mx, p[m]);
        float sum = 0.f;
        #pragma unroll
        for (int m = 0; m < M_NB; ++m) { p[m] = __expf(p[m] - mx); sum += p[m]; }
        float rs = 1.0f / sum;
        float2 acc = make_float2(0.f, 0.f);
        #pragma unroll
        for (int m = 0; m < M_NB; ++m) { acc.x += p[m] * z[m].x; acc.y += p[m] * z[m].y; }
        u.x = acc.x * rs + xn.x;
        u.y = acc.y * rs + xn.y;
        if (it < 2) {
            float sq = u.x * u.x + u.y * u.y;
            #pragma unroll
            for (int off = 32; off; off >>= 1) sq += __shfl_xor(sq, off);
            float scale = sq / ((sq + 1.0f) * fmaxf(sqrtf(sq), EPSN));
            u.x *= scale; u.y *= scale;
        }
    }
    *reinterpret_cast<float2*>(out + (size_t)node * D_DIM + 2 * lane) = u;
}

extern "C" void kernel_launch(void* const* d_in, const int* in_sizes, int n_in,
                              void* d_out, int out_size, void* d_ws, size_t ws_size,
                              hipStream_t stream) {
    const float* x  = (const float*)d_in[0];
    const int*   nb = (const int*)d_in[1];
    float* out = (float*)d_out;

    int n = in_sizes[0] / D_DIM;  // 50000
    int blocks = (n + 3) / 4;     // 4 waves (nodes/rows) per 256-thread block

    size_t xnb_bytes = (size_t)n * D_DIM * 2;  // 12.8 MB
    size_t need = xnb_bytes + (size_t)n * 4;   // + invn

    if (ws_size >= need) {
        unsigned int* xnb = (unsigned int*)d_ws;
        float* invn = (float*)((char*)d_ws + xnb_bytes);
        prep_kernel<<<blocks, 256, 0, stream>>>(x, xnb, invn, n);
        routing_bf16_kernel<<<blocks, 256, 0, stream>>>(x, nb, xnb, invn, out, n);
    } else {
        float* invn = (float*)d_ws;
        invnorm_kernel<<<blocks, 256, 0, stream>>>(x, invn, n);
        routing_kernel<<<blocks, 256, 0, stream>>>(x, nb, invn, out, n);
    }
}